// Round 11
// baseline (1078.543 us; speedup 1.0000x reference)
//
#include <hip/hip_runtime.h>
#include <math.h>

#define N_A   1024
#define HDIM  128
#define DIN   172
#define E_CNT 256
#define LP    72      // LDS pitch (bf16) for 64-wide GEMM tiles
#define NBLK  512     // persistent grid size (co-resident: LDS 18.4KB -> >=3 blk/CU)

typedef __attribute__((ext_vector_type(8))) short bf16x8;
typedef __attribute__((ext_vector_type(4))) float f32x4;

__device__ __forceinline__ unsigned short f2bf(float x) {
    unsigned int u = __float_as_uint(x);
    unsigned int r = (u + 0x7fffu + ((u >> 16) & 1u)) >> 16;
    return (unsigned short)r;
}

// Gauss-Legendre nodes/weights mapped to [0,1] (tau=1)
__constant__ float c_t[8] = {
    0.4082826787521751f, 0.2372337950418355f, 0.10166676129318665f, 0.019855071751231843f,
    0.5917173212478249f, 0.7627662049581645f, 0.8983332387068134f, 0.9801449282487682f};
__constant__ float c_w[8] = {
    0.181341891689181f, 0.15685332293894365f, 0.11119051722668725f, 0.05061426814518815f,
    0.181341891689181f, 0.15685332293894365f, 0.11119051722668725f, 0.05061426814518815f};

// ---------------------------------------------------------------------------
// device-scope grid barrier (counters zeroed by hipMemsetAsync before launch)
// ---------------------------------------------------------------------------
__device__ __forceinline__ void gbar(unsigned* cnt, int slot)
{
    __syncthreads();
    if (threadIdx.x == 0) {
        __threadfence();
        __hip_atomic_fetch_add(&cnt[slot], 1u, __ATOMIC_RELEASE, __HIP_MEMORY_SCOPE_AGENT);
        while (__hip_atomic_load(&cnt[slot], __ATOMIC_ACQUIRE, __HIP_MEMORY_SCOPE_AGENT)
               < (unsigned)NBLK)
            __builtin_amdgcn_s_sleep(2);
        __threadfence();
    }
    __syncthreads();
}

// ---------------------------------------------------------------------------
// conv task (b in [0,3552)) — identical math to round-10 conv_all
// ---------------------------------------------------------------------------
__device__ void conv_task(int b, int tid, unsigned short* shm,
    const float* L, const float* dL, const float* x_sub, const float* names,
    const int* src, const int* dst, const float* W_tune, const float* W_B1,
    const float* W_B2,
    unsigned short* Lb, unsigned short* dLb, unsigned short* LbT,
    unsigned short* dLbT, unsigned short* Xb, unsigned short* WtT,
    unsigned short* WB1T, unsigned short* WB2T)
{
    if (b < 2048) {
        const int t = b * 256 + tid;
        const float* s = (t < 262144) ? L : dL;
        unsigned short* d = (t < 262144) ? Lb : dLb;
        const int q = (t < 262144) ? t : t - 262144;
        float4 v = *(const float4*)(s + (size_t)q * 4);
        ushort4 o;
        o.x = f2bf(v.x); o.y = f2bf(v.y); o.z = f2bf(v.z); o.w = f2bf(v.w);
        *(ushort4*)(d + (size_t)q * 4) = o;
    } else if (b < 2816) {
        const int t = (b - 2048) * 256 + tid;
        const int i = t / 192, k = t - i * 192;
        float val = 0.f;
        if (k < DIN) val = x_sub[(size_t)i * DIN + k];
        else if (k == DIN) {
            if (i < E_CNT)          val = names[src[i]];
            else if (i < 2 * E_CNT) val = names[dst[i - E_CNT]];
        } else if (k == DIN + 1) {
            if (i < E_CNT)          val = names[dst[i]];
            else if (i < 2 * E_CNT) val = names[src[i - E_CNT]];
        }
        Xb[t] = f2bf(val);
    } else if (b < 2912) {
        const int t = (b - 2816) * 256 + tid;
        const int j = t / 192, k = t - j * 192;
        WtT[t] = (k < DIN + 2) ? f2bf(W_tune[k * HDIM + j]) : (unsigned short)0;
    } else if (b < 3040) {
        const int t = (b - 2912) * 256 + tid;
        const int half = t >> 14, tt = t & 16383;
        const int j = tt >> 7, k = tt & 127;
        (half ? WB2T : WB1T)[tt] = f2bf((half ? W_B2 : W_B1)[k * HDIM + j]);
    } else {
        unsigned short (*tl)[72] = (unsigned short (*)[72])shm;
        const int t = b - 3040;
        const float* s = (t < 256) ? L : dL;
        unsigned short* d = (t < 256) ? LbT : dLbT;
        const int tile = t & 255, tr = tile >> 4, tc = tile & 15;
        const int row = tid >> 2, cg = (tid & 3) << 4;
        #pragma unroll
        for (int e = 0; e < 4; ++e) {
            float4 v = *(const float4*)(s + (size_t)(tr * 64 + row) * 1024 + tc * 64 + cg + e * 4);
            tl[row][cg + e * 4 + 0] = f2bf(v.x);
            tl[row][cg + e * 4 + 1] = f2bf(v.y);
            tl[row][cg + e * 4 + 2] = f2bf(v.z);
            tl[row][cg + e * 4 + 3] = f2bf(v.w);
        }
        __syncthreads();
        unsigned short* drow = d + (size_t)(tc * 64 + row) * 1024 + tr * 64 + cg;
        #pragma unroll
        for (int e = 0; e < 4; ++e) {
            ushort4 o;
            o.x = tl[cg + e * 4 + 0][row];
            o.y = tl[cg + e * 4 + 1][row];
            o.z = tl[cg + e * 4 + 2][row];
            o.w = tl[cg + e * 4 + 3][row];
            *(ushort4*)(drow + e * 4) = o;
        }
        __syncthreads();
    }
}

// ---------------------------------------------------------------------------
// single-A 64x64 MFMA core (unchanged)
// ---------------------------------------------------------------------------
__device__ __forceinline__ void core_sa(
    const unsigned short* __restrict__ ag, const unsigned short* __restrict__ bg,
    unsigned short* As, unsigned short* Bs, int klen,
    int srow, int skc, int wrow, int wcol, int fr, int fk, f32x4 (&acc)[2][2])
{
    bf16x8 pa0 = *(const bf16x8*)ag, pa1 = *(const bf16x8*)(ag + 8);
    bf16x8 pb0 = *(const bf16x8*)bg, pb1 = *(const bf16x8*)(bg + 8);
    for (int k0 = 0; k0 < klen; k0 += 64) {
        __syncthreads();
        *(bf16x8*)&As[srow * LP + skc] = pa0; *(bf16x8*)&As[srow * LP + skc + 8] = pa1;
        *(bf16x8*)&Bs[srow * LP + skc] = pb0; *(bf16x8*)&Bs[srow * LP + skc + 8] = pb1;
        __syncthreads();
        if (k0 + 64 < klen) {
            pa0 = *(const bf16x8*)(ag + k0 + 64); pa1 = *(const bf16x8*)(ag + k0 + 72);
            pb0 = *(const bf16x8*)(bg + k0 + 64); pb1 = *(const bf16x8*)(bg + k0 + 72);
        }
        #pragma unroll
        for (int h = 0; h < 2; ++h) {
            const int ko = h * 32 + fk;
            bf16x8 a0 = *(const bf16x8*)&As[(wrow + fr) * LP + ko];
            bf16x8 a1 = *(const bf16x8*)&As[(wrow + 16 + fr) * LP + ko];
            bf16x8 b0 = *(const bf16x8*)&Bs[(wcol + fr) * LP + ko];
            bf16x8 b1 = *(const bf16x8*)&Bs[(wcol + 16 + fr) * LP + ko];
            acc[0][0] = __builtin_amdgcn_mfma_f32_16x16x32_bf16(a0, b0, acc[0][0], 0, 0, 0);
            acc[0][1] = __builtin_amdgcn_mfma_f32_16x16x32_bf16(a0, b1, acc[0][1], 0, 0, 0);
            acc[1][0] = __builtin_amdgcn_mfma_f32_16x16x32_bf16(a1, b0, acc[1][0], 0, 0, 0);
            acc[1][1] = __builtin_amdgcn_mfma_f32_16x16x32_bf16(a1, b1, acc[1][1], 0, 0, 0);
        }
    }
}

// ---------------------------------------------------------------------------
// p12 task (t in [0,512)): P1 = dL@L, P2 = dL@dL via transpose trick
// ---------------------------------------------------------------------------
__device__ void p12_task(int t, int tid, unsigned short* shm,
    const unsigned short* LbT, const unsigned short* dLbT,
    const unsigned short* dLb, unsigned short* P1b, unsigned short* P2b)
{
    const int bx = t >> 4, rb = t & 15;
    const int unit = bx >> 4, cb = bx & 15;
    const unsigned short* A = unit ? dLbT : LbT;
    unsigned short* O = unit ? P2b : P1b;
    unsigned short* As = shm; unsigned short* Bs = shm + 64 * LP;
    const int srow = tid >> 2, skc = (tid & 3) << 4;
    const unsigned short* ag = A   + (size_t)(rb * 64 + srow) * 1024 + skc;
    const unsigned short* bg = dLb + (size_t)(cb * 64 + srow) * 1024 + skc;
    const int lane = tid & 63, w = tid >> 6;
    const int wrow = (w >> 1) * 32, wcol = (w & 1) * 32;
    const int fr = lane & 15, fg = lane >> 4, fk = fg << 3;

    f32x4 acc[2][2] = {};
    core_sa(ag, bg, As, Bs, 1024, srow, skc, wrow, wcol, fr, fk, acc);

    #pragma unroll
    for (int m = 0; m < 2; ++m) {
        const int gm = rb * 64 + wrow + m * 16 + fg * 4;
        #pragma unroll
        for (int n = 0; n < 2; ++n) {
            const int gj = cb * 64 + wcol + n * 16 + fr;
            ushort4 tv;
            tv.x = f2bf(acc[m][n][0]); tv.y = f2bf(acc[m][n][1]);
            tv.z = f2bf(acc[m][n][2]); tv.w = f2bf(acc[m][n][3]);
            *(ushort4*)&O[(size_t)gj * 1024 + gm] = tv;
        }
    }
}

// ---------------------------------------------------------------------------
// zt task (t in [0,32)): zt = Xb @ WtT^T + b_tune
// ---------------------------------------------------------------------------
__device__ void zt_task(int t, int tid, unsigned short* shm,
    const unsigned short* Xb, const unsigned short* WtT,
    const float* b_tune, float* zt)
{
    const int cb = t >> 4, rb = t & 15;
    unsigned short* As = shm; unsigned short* Bs = shm + 64 * LP;
    const int srow = tid >> 2, skc = (tid & 3) << 4;
    const unsigned short* ag = Xb  + (size_t)(rb * 64 + srow) * 192 + skc;
    const unsigned short* bg = WtT + (size_t)(cb * 64 + srow) * 192 + skc;
    const int lane = tid & 63, w = tid >> 6;
    const int wrow = (w >> 1) * 32, wcol = (w & 1) * 32;
    const int fr = lane & 15, fg = lane >> 4, fk = fg << 3;

    f32x4 acc[2][2] = {};
    core_sa(ag, bg, As, Bs, 192, srow, skc, wrow, wcol, fr, fk, acc);

    #pragma unroll
    for (int m = 0; m < 2; ++m) {
        const int gm = rb * 64 + wrow + m * 16 + fg * 4;
        #pragma unroll
        for (int n = 0; n < 2; ++n) {
            const int gj = cb * 64 + wcol + n * 16 + fr;
            const float bb = b_tune[gj];
            #pragma unroll
            for (int r = 0; r < 4; ++r)
                zt[(size_t)(gm + r) * HDIM + gj] = acc[m][n][r] + bb;
        }
    }
}

// ---------------------------------------------------------------------------
// 128-wide row reduction (per 128-thread group; whole 256-thread block syncs)
// ---------------------------------------------------------------------------
__device__ __forceinline__ float rowsum128(float v, float* red, int j)
{
    #pragma unroll
    for (int o = 32; o > 0; o >>= 1) v += __shfl_xor(v, o, 64);
    if ((j & 63) == 0) red[j >> 6] = v;
    __syncthreads();
    const float t = red[0] + red[1];
    __syncthreads();
    return t;
}

__device__ __forceinline__ void rms_core(
    float x, int i, int j,
    const float* rms_scale, const float* W_dt, const float* b_dt,
    const float* A_log, const float* m_vec, const int* act,
    unsigned short* xnb, float* VU, unsigned short* VUt, float* dlt, float* red)
{
    const float ss = rowsum128(x * x, red, j);
    const float rms = sqrtf(ss) * 0.08838834764831845f;   // /sqrt(128)
    const float xn = rms_scale[j] * x / (rms + 1e-8f);
    const float dsum = rowsum128(xn * W_dt[j], red, j);
    const float dd = dsum + b_dt[0];
    const float delta = dd > 0.f ? dd + log1pf(expf(-dd)) : log1pf(expf(dd));
    xnb[(size_t)i * HDIM + j] = f2bf(xn);
    const float U = m_vec[(size_t)act[i] * HDIM + j] * expf(-delta * expf(A_log[j]));
    VU[(size_t)i * 256 + 128 + j] = U;
    VUt[(size_t)(128 + j) * 1024 + i] = f2bf(U);
    if (j == 0) dlt[i] = delta;
}

__device__ __forceinline__ float post_elem(float y1, float y2, float y3, float s,
                                           float g, float u, float dA)
{
    const float bl = -0.1f * y1 + 0.01f * y2;
    const float cq = 0.005f * y3;
    float integ = 0.f;
    #pragma unroll
    for (int k = 0; k < 8; ++k) {
        const float t = c_t[k];
        integ += c_w[k] * (g + t * bl + t * t * cq) * expf(dA * t);
    }
    return u - 0.1f * s + integ;
}

// ---------------------------------------------------------------------------
// bz2 task (t in [0,32)): V = (xnb @ WBT^T + b_B) * dlt
// ---------------------------------------------------------------------------
__device__ void bz2_task(int t, int tid, unsigned short* shm,
    const unsigned short* xnb, const unsigned short* WBT,
    const float* b_B, const float* dlt, float* VU, unsigned short* VUt)
{
    const int cb = t >> 4, rb = t & 15;
    unsigned short* As = shm; unsigned short* Bs = shm + 64 * LP;
    const int srow = tid >> 2, skc = (tid & 3) << 4;
    const unsigned short* ag = xnb + (size_t)(rb * 64 + srow) * HDIM + skc;
    const unsigned short* bg = WBT + (size_t)(cb * 64 + srow) * HDIM + skc;
    const int lane = tid & 63, w = tid >> 6;
    const int wrow = (w >> 1) * 32, wcol = (w & 1) * 32;
    const int fr = lane & 15, fg = lane >> 4, fk = fg << 3;

    f32x4 acc[2][2] = {};
    core_sa(ag, bg, As, Bs, 128, srow, skc, wrow, wcol, fr, fk, acc);

    #pragma unroll
    for (int m = 0; m < 2; ++m) {
        const int gm = rb * 64 + wrow + m * 16 + fg * 4;
        #pragma unroll
        for (int n = 0; n < 2; ++n) {
            const int col = cb * 64 + wcol + n * 16 + fr;
            const float bb = b_B[col];
            float vv[4];
            #pragma unroll
            for (int r = 0; r < 4; ++r) {
                vv[r] = (acc[m][n][r] + bb) * dlt[gm + r];
                VU[(size_t)(gm + r) * 256 + col] = vv[r];
            }
            ushort4 tv;
            tv.x = f2bf(vv[0]); tv.y = f2bf(vv[1]); tv.z = f2bf(vv[2]); tv.w = f2bf(vv[3]);
            *(ushort4*)&VUt[(size_t)col * 1024 + gm] = tv;
        }
    }
}

// ---------------------------------------------------------------------------
// GA task (t in [0,128)): slots 0,1 -> G = V-0.1LV ; 2,3 -> T = U-0.1LU-0.05dLU
// ---------------------------------------------------------------------------
__device__ void ga_task(int t, int tid, unsigned short* shm,
    const unsigned short* Lb, const unsigned short* dLb,
    const unsigned short* VUt, const float* VU,
    unsigned short* GTt, float* Gf)
{
    const int slot = t >> 5, rb = t & 31;
    const bool typeT = slot >= 2;
    const int cb = typeT ? slot - 2 : slot;
    const int bn0 = (typeT ? 128 : 0) + cb * 64;

    unsigned short* AsL = shm;
    unsigned short* AsD = shm + 32 * LP;
    unsigned short* Bs  = shm + 64 * LP;

    const int sar = tid >> 3, sac = (tid & 7) << 3;
    const int sbr = tid >> 2, sbc = (tid & 3) << 4;

    const unsigned short* aL = Lb  + (size_t)(rb * 32 + sar) * 1024 + sac;
    const unsigned short* aD = dLb + (size_t)(rb * 32 + sar) * 1024 + sac;
    const unsigned short* bg = VUt + (size_t)(bn0 + sbr) * 1024 + sbc;

    const int lane = tid & 63, w = tid >> 6;
    const int fr = lane & 15, fg = lane >> 4, fk = fg << 3;

    f32x4 acc[2] = {};
    f32x4 acc2[2] = {};

    bf16x8 pa = *(const bf16x8*)aL;
    bf16x8 pd = {};
    if (typeT) pd = *(const bf16x8*)aD;
    bf16x8 pb0 = *(const bf16x8*)bg, pb1 = *(const bf16x8*)(bg + 8);

    for (int k0 = 0; k0 < 1024; k0 += 64) {
        __syncthreads();
        *(bf16x8*)&AsL[sar * LP + sac] = pa;
        if (typeT) *(bf16x8*)&AsD[sar * LP + sac] = pd;
        *(bf16x8*)&Bs[sbr * LP + sbc] = pb0; *(bf16x8*)&Bs[sbr * LP + sbc + 8] = pb1;
        __syncthreads();
        if (k0 + 64 < 1024) {
            pa = *(const bf16x8*)(aL + k0 + 64);
            if (typeT) pd = *(const bf16x8*)(aD + k0 + 64);
            pb0 = *(const bf16x8*)(bg + k0 + 64); pb1 = *(const bf16x8*)(bg + k0 + 72);
        }
        #pragma unroll
        for (int h = 0; h < 2; ++h) {
            const int ko = h * 32 + fk;
            bf16x8 a0 = *(const bf16x8*)&AsL[fr * LP + ko];
            bf16x8 a1 = *(const bf16x8*)&AsL[(16 + fr) * LP + ko];
            bf16x8 b0 = *(const bf16x8*)&Bs[(w * 16 + fr) * LP + ko];
            acc[0] = __builtin_amdgcn_mfma_f32_16x16x32_bf16(a0, b0, acc[0], 0, 0, 0);
            acc[1] = __builtin_amdgcn_mfma_f32_16x16x32_bf16(a1, b0, acc[1], 0, 0, 0);
            if (typeT) {
                bf16x8 d0 = *(const bf16x8*)&AsD[fr * LP + ko];
                bf16x8 d1 = *(const bf16x8*)&AsD[(16 + fr) * LP + ko];
                acc2[0] = __builtin_amdgcn_mfma_f32_16x16x32_bf16(d0, b0, acc2[0], 0, 0, 0);
                acc2[1] = __builtin_amdgcn_mfma_f32_16x16x32_bf16(d1, b0, acc2[1], 0, 0, 0);
            }
        }
    }

    #pragma unroll
    for (int m = 0; m < 2; ++m) {
        const int gm = rb * 32 + m * 16 + fg * 4;
        const int gj = cb * 64 + w * 16 + fr;
        float gv[4];
        #pragma unroll
        for (int r = 0; r < 4; ++r) {
            if (!typeT)
                gv[r] = VU[(size_t)(gm + r) * 256 + gj] - 0.1f * acc[m][r];
            else
                gv[r] = VU[(size_t)(gm + r) * 256 + 128 + gj]
                      - 0.1f * acc[m][r] - 0.05f * acc2[m][r];
        }
        ushort4 tv; tv.x = f2bf(gv[0]); tv.y = f2bf(gv[1]); tv.z = f2bf(gv[2]); tv.w = f2bf(gv[3]);
        *(ushort4*)&GTt[(size_t)((typeT ? 128 : 0) + gj) * 1024 + gm] = tv;
        if (!typeT) {
            #pragma unroll
            for (int r = 0; r < 4; ++r) Gf[(size_t)(gm + r) * 128 + gj] = gv[r];
        }
    }
}

// ---------------------------------------------------------------------------
// GB task (t in [0,128)): unit0 Y1=dL@G, unit1 Y2=P1@G, unit2 Y3=P2@G, unit3 S=dL@T
// ---------------------------------------------------------------------------
__device__ void gb_task(int t, int tid, unsigned short* shm,
    const unsigned short* dLb, const unsigned short* P1b,
    const unsigned short* P2b, const unsigned short* GTt,
    float* Y1f, float* Y2f, float* Y3f, float* Sf)
{
    const int bx = t >> 4, rb = t & 15;
    const int unit = bx >> 1, cb = bx & 1;
    const unsigned short* A = (unit == 1) ? P1b : (unit == 2) ? P2b : dLb;
    const int bn0 = (unit == 3 ? 128 : 0) + cb * 64;
    float* O = unit == 0 ? Y1f : unit == 1 ? Y2f : unit == 2 ? Y3f : Sf;

    unsigned short* As = shm; unsigned short* Bs = shm + 64 * LP;
    const int srow = tid >> 2, skc = (tid & 3) << 4;
    const unsigned short* ag = A   + (size_t)(rb * 64 + srow) * 1024 + skc;
    const unsigned short* bg = GTt + (size_t)(bn0 + srow) * 1024 + skc;

    const int lane = tid & 63, w = tid >> 6;
    const int wrow = (w >> 1) * 32, wcol = (w & 1) * 32;
    const int fr = lane & 15, fg = lane >> 4, fk = fg << 3;

    f32x4 acc[2][2] = {};
    core_sa(ag, bg, As, Bs, 1024, srow, skc, wrow, wcol, fr, fk, acc);

    #pragma unroll
    for (int m = 0; m < 2; ++m) {
        const int gm = rb * 64 + wrow + m * 16 + fg * 4;
        #pragma unroll
        for (int n = 0; n < 2; ++n) {
            const int gj = cb * 64 + wcol + n * 16 + fr;
            #pragma unroll
            for (int r = 0; r < 4; ++r) O[(size_t)(gm + r) * 128 + gj] = acc[m][n][r];
        }
    }
}

// ---------------------------------------------------------------------------
// the mega kernel: 11 phases, 10 grid barriers
// ---------------------------------------------------------------------------
__global__ __launch_bounds__(256)
void mega(const float* L, const float* dL, const float* x_sub,
          const float* m1, const float* m2, const float* names,
          const float* rms1, const float* rms2,
          const float* W_tune, const float* b_tune,
          const float* W_B1, const float* b_B1,
          const float* W_B2, const float* b_B2,
          const float* W_dt, const float* b_dt,
          const float* A1, const float* A2,
          const int* src, const int* dst, const int* act,
          float* zt, float* VU, float* Gf, float* Y1f, float* Y2f,
          float* Y3f, float* Sf, float* dlt1, float* dlt2,
          unsigned short* Lb, unsigned short* dLb, unsigned short* LbT,
          unsigned short* dLbT, unsigned short* P1b, unsigned short* P2b,
          unsigned short* VUt, unsigned short* GTt, unsigned short* Xb,
          unsigned short* WtT, unsigned short* WB1T, unsigned short* WB2T,
          unsigned short* xnb, unsigned* cnt, float* out)
{
    __shared__ unsigned short shm[128 * LP];   // 18432 B, aliased per phase
    const int bid = blockIdx.x, tid = threadIdx.x;
    const int g = tid >> 7, j = tid & 127;
    float* redf = (float*)shm;

    // ph0: conversions / transposes
    for (int t = bid; t < 3552; t += NBLK)
        conv_task(t, tid, shm, L, dL, x_sub, names, src, dst, W_tune, W_B1, W_B2,
                  Lb, dLb, LbT, dLbT, Xb, WtT, WB1T, WB2T);
    gbar(cnt, 0);

    // ph1: P1,P2 (512 tasks) + zt (32 tasks on blocks 0..31)
    p12_task(bid, tid, shm, LbT, dLbT, dLb, P1b, P2b);
    if (bid < 32) zt_task(bid, tid, shm, Xb, WtT, b_tune, zt);
    gbar(cnt, 1);

    // ph2: stage-1 pre (rms/delta/U), 2 rows per block
    {
        const int i = bid * 2 + g;
        rms_core(zt[(size_t)i * HDIM + j], i, j, rms1, W_dt, b_dt, A1, m1, act,
                 xnb, VU, VUt, dlt1, redf + 2 * g);
    }
    gbar(cnt, 2);

    // ph3: bz2 stage 1
    if (bid < 32) bz2_task(bid, tid, shm, xnb, WB1T, b_B1, dlt1, VU, VUt);
    gbar(cnt, 3);

    // ph4: GA stage 1
    if (bid < 128) ga_task(bid, tid, shm, Lb, dLb, VUt, VU, GTt, Gf);
    gbar(cnt, 4);

    // ph5: GB stage 1
    if (bid < 128) gb_task(bid, tid, shm, dLb, P1b, P2b, GTt, Y1f, Y2f, Y3f, Sf);
    gbar(cnt, 5);

    // ph6: mid — post(stage1) -> out[0]; x2 = zt+gelu; pre(stage2)
    {
        const int i = bid * 2 + g;
        const int idx = i * HDIM + j;
        const float dA = -dlt1[i] * expf(A1[j]);
        const float o1 = post_elem(Y1f[idx], Y2f[idx], Y3f[idx], Sf[idx], Gf[idx],
                                   VU[(size_t)i * 256 + 128 + j], dA);
        out[idx] = o1;
        const float g3 = o1 * o1 * o1;
        const float gel = 0.5f * o1 * (1.0f + tanhf(0.7978845608028654f * (o1 + 0.044715f * g3)));
        const float x = zt[idx] + gel;
        rms_core(x, i, j, rms2, W_dt, b_dt, A2, m2, act, xnb, VU, VUt, dlt2, redf + 2 * g);
    }
    gbar(cnt, 6);

    // ph7: bz2 stage 2
    if (bid < 32) bz2_task(bid, tid, shm, xnb, WB2T, b_B2, dlt2, VU, VUt);
    gbar(cnt, 7);

    // ph8: GA stage 2
    if (bid < 128) ga_task(bid, tid, shm, Lb, dLb, VUt, VU, GTt, Gf);
    gbar(cnt, 8);

    // ph9: GB stage 2
    if (bid < 128) gb_task(bid, tid, shm, dLb, P1b, P2b, GTt, Y1f, Y2f, Y3f, Sf);
    gbar(cnt, 9);

    // ph10: tail — post(stage2) -> out[1]
    {
        const int idx = bid * 256 + tid;        // 512*256 = 131072 exactly
        const int i = idx >> 7, jj = idx & 127;
        const float dA = -dlt2[i] * expf(A2[jj]);
        out[131072 + idx] = post_elem(Y1f[idx], Y2f[idx], Y3f[idx], Sf[idx], Gf[idx],
                                      VU[(size_t)i * 256 + 128 + jj], dA);
    }
}

// ---------------------------------------------------------------------------
extern "C" void kernel_launch(void* const* d_in, const int* in_sizes, int n_in,
                              void* d_out, int out_size, void* d_ws, size_t ws_size,
                              hipStream_t stream)
{
    const float* L      = (const float*)d_in[0];
    const float* dL     = (const float*)d_in[1];
    const float* x_sub  = (const float*)d_in[2];
    const float* m1     = (const float*)d_in[3];
    const float* m2     = (const float*)d_in[4];
    const float* names  = (const float*)d_in[5];
    const float* rms1   = (const float*)d_in[6];
    const float* rms2   = (const float*)d_in[7];
    const float* W_tune = (const float*)d_in[8];
    const float* b_tune = (const float*)d_in[9];
    const float* W_B1   = (const float*)d_in[10];
    const float* b_B1   = (const float*)d_in[11];
    const float* W_B2   = (const float*)d_in[12];
    const float* b_B2   = (const float*)d_in[13];
    const float* W_dt   = (const float*)d_in[14];
    const float* b_dt   = (const float*)d_in[15];
    const float* A1     = (const float*)d_in[16];
    const float* A2     = (const float*)d_in[17];
    const int*   src    = (const int*)d_in[18];
    const int*   dst    = (const int*)d_in[19];
    const int*   act    = (const int*)d_in[20];
    float* out = (float*)d_out;

    // Workspace layout (~19 MB): barrier counters first (64 B), then buffers
    unsigned* cnt = (unsigned*)d_ws;
    float* ws   = (float*)((char*)d_ws + 64);
    float* zt   = ws;                    // 131072
    float* VU   = zt   + 131072;         // 262144  fp32 [V|U]
    float* Gf   = VU   + 262144;         // 131072
    float* Y1f  = Gf   + 131072;         // 131072
    float* Y2f  = Y1f  + 131072;         // 131072
    float* Y3f  = Y2f  + 131072;         // 131072
    float* Sf   = Y3f  + 131072;         // 131072
    float* dlt1 = Sf   + 131072;         // 1024
    float* dlt2 = dlt1 + 1024;           // 1024
    unsigned short* Lb    = (unsigned short*)(dlt2 + 1024);
    unsigned short* dLb   = Lb    + 1048576;
    unsigned short* LbT   = dLb   + 1048576;
    unsigned short* dLbT  = LbT   + 1048576;
    unsigned short* P1b   = dLbT  + 1048576;
    unsigned short* P2b   = P1b   + 1048576;
    unsigned short* VUt   = P2b   + 1048576;
    unsigned short* GTt   = VUt   + 262144;
    unsigned short* Xb    = GTt   + 262144;
    unsigned short* WtT   = Xb    + 196608;
    unsigned short* WB1T  = WtT   + 24576;
    unsigned short* WB2T  = WB1T  + 16384;
    unsigned short* xnb   = WB2T  + 16384;

    hipMemsetAsync(cnt, 0, 16 * sizeof(unsigned), stream);

    mega<<<dim3(NBLK), dim3(256), 0, stream>>>(
        L, dL, x_sub, m1, m2, names, rms1, rms2, W_tune, b_tune,
        W_B1, b_B1, W_B2, b_B2, W_dt, b_dt, A1, A2, src, dst, act,
        zt, VU, Gf, Y1f, Y2f, Y3f, Sf, dlt1, dlt2,
        Lb, dLb, LbT, dLbT, P1b, P2b, VUt, GTt, Xb, WtT, WB1T, WB2T,
        xnb, cnt, out);
}

// Round 12
// 240.342 us; speedup vs baseline: 4.4875x; 4.4875x over previous
//
#include <hip/hip_runtime.h>
#include <math.h>

#define N_A   1024
#define HDIM  128
#define DIN   172
#define E_CNT 256
#define LP    72      // LDS pitch (bf16) for 64-wide GEMM tiles
#define NBLK  512     // persistent grid size (co-resident: LDS 18.4KB, 2 blk/CU)

typedef __attribute__((ext_vector_type(8))) short bf16x8;
typedef __attribute__((ext_vector_type(4))) float f32x4;

__device__ __forceinline__ unsigned short f2bf(float x) {
    unsigned int u = __float_as_uint(x);
    unsigned int r = (u + 0x7fffu + ((u >> 16) & 1u)) >> 16;
    return (unsigned short)r;
}

// Gauss-Legendre nodes/weights mapped to [0,1] (tau=1)
__constant__ float c_t[8] = {
    0.4082826787521751f, 0.2372337950418355f, 0.10166676129318665f, 0.019855071751231843f,
    0.5917173212478249f, 0.7627662049581645f, 0.8983332387068134f, 0.9801449282487682f};
__constant__ float c_w[8] = {
    0.181341891689181f, 0.15685332293894365f, 0.11119051722668725f, 0.05061426814518815f,
    0.181341891689181f, 0.15685332293894365f, 0.11119051722668725f, 0.05061426814518815f};

// ---------------------------------------------------------------------------
// device-scope grid barrier, contention/cache-maintenance-safe version:
//  - arrive counter: RELAXED fetch_add on its own 128B line (no pollers on it)
//  - release flag: 4 replicated lines, polled with RELAXED loads (no buffer_inv
//    per poll!), written once by the last arriver
//  - exactly one RELEASE fence per arrival and one ACQUIRE fence per departure
// sync layout (u32 idx): cnt[slot*32], flags at 512 + (slot*4+k)*32
// ---------------------------------------------------------------------------
__device__ __forceinline__ void gbar(unsigned* sync, int slot, int bid)
{
    __syncthreads();
    if (threadIdx.x == 0) {
        __builtin_amdgcn_fence(__ATOMIC_RELEASE, "agent");
        const unsigned old = __hip_atomic_fetch_add(&sync[slot * 32], 1u,
                                __ATOMIC_RELAXED, __HIP_MEMORY_SCOPE_AGENT);
        unsigned* flags = sync + 512;
        if (old == (unsigned)(NBLK - 1)) {
            #pragma unroll
            for (int k = 0; k < 4; ++k)
                __hip_atomic_store(&flags[(slot * 4 + k) * 32], 1u,
                                   __ATOMIC_RELAXED, __HIP_MEMORY_SCOPE_AGENT);
        } else {
            unsigned* f = &flags[(slot * 4 + (bid & 3)) * 32];
            while (__hip_atomic_load(f, __ATOMIC_RELAXED,
                                     __HIP_MEMORY_SCOPE_AGENT) == 0u)
                __builtin_amdgcn_s_sleep(8);
        }
        __builtin_amdgcn_fence(__ATOMIC_ACQUIRE, "agent");
    }
    __syncthreads();
}

// ---------------------------------------------------------------------------
// conv task (b in [0,3552)) — identical math to round-10 conv_all
// ---------------------------------------------------------------------------
__device__ void conv_task(int b, int tid, unsigned short* shm,
    const float* L, const float* dL, const float* x_sub, const float* names,
    const int* src, const int* dst, const float* W_tune, const float* W_B1,
    const float* W_B2,
    unsigned short* Lb, unsigned short* dLb, unsigned short* LbT,
    unsigned short* dLbT, unsigned short* Xb, unsigned short* WtT,
    unsigned short* WB1T, unsigned short* WB2T)
{
    if (b < 2048) {
        const int t = b * 256 + tid;
        const float* s = (t < 262144) ? L : dL;
        unsigned short* d = (t < 262144) ? Lb : dLb;
        const int q = (t < 262144) ? t : t - 262144;
        float4 v = *(const float4*)(s + (size_t)q * 4);
        ushort4 o;
        o.x = f2bf(v.x); o.y = f2bf(v.y); o.z = f2bf(v.z); o.w = f2bf(v.w);
        *(ushort4*)(d + (size_t)q * 4) = o;
    } else if (b < 2816) {
        const int t = (b - 2048) * 256 + tid;
        const int i = t / 192, k = t - i * 192;
        float val = 0.f;
        if (k < DIN) val = x_sub[(size_t)i * DIN + k];
        else if (k == DIN) {
            if (i < E_CNT)          val = names[src[i]];
            else if (i < 2 * E_CNT) val = names[dst[i - E_CNT]];
        } else if (k == DIN + 1) {
            if (i < E_CNT)          val = names[dst[i]];
            else if (i < 2 * E_CNT) val = names[src[i - E_CNT]];
        }
        Xb[t] = f2bf(val);
    } else if (b < 2912) {
        const int t = (b - 2816) * 256 + tid;
        const int j = t / 192, k = t - j * 192;
        WtT[t] = (k < DIN + 2) ? f2bf(W_tune[k * HDIM + j]) : (unsigned short)0;
    } else if (b < 3040) {
        const int t = (b - 2912) * 256 + tid;
        const int half = t >> 14, tt = t & 16383;
        const int j = tt >> 7, k = tt & 127;
        (half ? WB2T : WB1T)[tt] = f2bf((half ? W_B2 : W_B1)[k * HDIM + j]);
    } else {
        unsigned short (*tl)[72] = (unsigned short (*)[72])shm;
        const int t = b - 3040;
        const float* s = (t < 256) ? L : dL;
        unsigned short* d = (t < 256) ? LbT : dLbT;
        const int tile = t & 255, tr = tile >> 4, tc = tile & 15;
        const int row = tid >> 2, cg = (tid & 3) << 4;
        #pragma unroll
        for (int e = 0; e < 4; ++e) {
            float4 v = *(const float4*)(s + (size_t)(tr * 64 + row) * 1024 + tc * 64 + cg + e * 4);
            tl[row][cg + e * 4 + 0] = f2bf(v.x);
            tl[row][cg + e * 4 + 1] = f2bf(v.y);
            tl[row][cg + e * 4 + 2] = f2bf(v.z);
            tl[row][cg + e * 4 + 3] = f2bf(v.w);
        }
        __syncthreads();
        unsigned short* drow = d + (size_t)(tc * 64 + row) * 1024 + tr * 64 + cg;
        #pragma unroll
        for (int e = 0; e < 4; ++e) {
            ushort4 o;
            o.x = tl[cg + e * 4 + 0][row];
            o.y = tl[cg + e * 4 + 1][row];
            o.z = tl[cg + e * 4 + 2][row];
            o.w = tl[cg + e * 4 + 3][row];
            *(ushort4*)(drow + e * 4) = o;
        }
        __syncthreads();
    }
}

// ---------------------------------------------------------------------------
// single-A 64x64 MFMA core (unchanged)
// ---------------------------------------------------------------------------
__device__ __forceinline__ void core_sa(
    const unsigned short* __restrict__ ag, const unsigned short* __restrict__ bg,
    unsigned short* As, unsigned short* Bs, int klen,
    int srow, int skc, int wrow, int wcol, int fr, int fk, f32x4 (&acc)[2][2])
{
    bf16x8 pa0 = *(const bf16x8*)ag, pa1 = *(const bf16x8*)(ag + 8);
    bf16x8 pb0 = *(const bf16x8*)bg, pb1 = *(const bf16x8*)(bg + 8);
    for (int k0 = 0; k0 < klen; k0 += 64) {
        __syncthreads();
        *(bf16x8*)&As[srow * LP + skc] = pa0; *(bf16x8*)&As[srow * LP + skc + 8] = pa1;
        *(bf16x8*)&Bs[srow * LP + skc] = pb0; *(bf16x8*)&Bs[srow * LP + skc + 8] = pb1;
        __syncthreads();
        if (k0 + 64 < klen) {
            pa0 = *(const bf16x8*)(ag + k0 + 64); pa1 = *(const bf16x8*)(ag + k0 + 72);
            pb0 = *(const bf16x8*)(bg + k0 + 64); pb1 = *(const bf16x8*)(bg + k0 + 72);
        }
        #pragma unroll
        for (int h = 0; h < 2; ++h) {
            const int ko = h * 32 + fk;
            bf16x8 a0 = *(const bf16x8*)&As[(wrow + fr) * LP + ko];
            bf16x8 a1 = *(const bf16x8*)&As[(wrow + 16 + fr) * LP + ko];
            bf16x8 b0 = *(const bf16x8*)&Bs[(wcol + fr) * LP + ko];
            bf16x8 b1 = *(const bf16x8*)&Bs[(wcol + 16 + fr) * LP + ko];
            acc[0][0] = __builtin_amdgcn_mfma_f32_16x16x32_bf16(a0, b0, acc[0][0], 0, 0, 0);
            acc[0][1] = __builtin_amdgcn_mfma_f32_16x16x32_bf16(a0, b1, acc[0][1], 0, 0, 0);
            acc[1][0] = __builtin_amdgcn_mfma_f32_16x16x32_bf16(a1, b0, acc[1][0], 0, 0, 0);
            acc[1][1] = __builtin_amdgcn_mfma_f32_16x16x32_bf16(a1, b1, acc[1][1], 0, 0, 0);
        }
    }
}

// ---------------------------------------------------------------------------
// p12 task (t in [0,512)): P1 = dL@L, P2 = dL@dL via transpose trick
// ---------------------------------------------------------------------------
__device__ void p12_task(int t, int tid, unsigned short* shm,
    const unsigned short* LbT, const unsigned short* dLbT,
    const unsigned short* dLb, unsigned short* P1b, unsigned short* P2b)
{
    const int bx = t >> 4, rb = t & 15;
    const int unit = bx >> 4, cb = bx & 15;
    const unsigned short* A = unit ? dLbT : LbT;
    unsigned short* O = unit ? P2b : P1b;
    unsigned short* As = shm; unsigned short* Bs = shm + 64 * LP;
    const int srow = tid >> 2, skc = (tid & 3) << 4;
    const unsigned short* ag = A   + (size_t)(rb * 64 + srow) * 1024 + skc;
    const unsigned short* bg = dLb + (size_t)(cb * 64 + srow) * 1024 + skc;
    const int lane = tid & 63, w = tid >> 6;
    const int wrow = (w >> 1) * 32, wcol = (w & 1) * 32;
    const int fr = lane & 15, fg = lane >> 4, fk = fg << 3;

    f32x4 acc[2][2] = {};
    core_sa(ag, bg, As, Bs, 1024, srow, skc, wrow, wcol, fr, fk, acc);

    #pragma unroll
    for (int m = 0; m < 2; ++m) {
        const int gm = rb * 64 + wrow + m * 16 + fg * 4;
        #pragma unroll
        for (int n = 0; n < 2; ++n) {
            const int gj = cb * 64 + wcol + n * 16 + fr;
            ushort4 tv;
            tv.x = f2bf(acc[m][n][0]); tv.y = f2bf(acc[m][n][1]);
            tv.z = f2bf(acc[m][n][2]); tv.w = f2bf(acc[m][n][3]);
            *(ushort4*)&O[(size_t)gj * 1024 + gm] = tv;
        }
    }
}

// ---------------------------------------------------------------------------
// zt task (t in [0,32)): zt = Xb @ WtT^T + b_tune
// ---------------------------------------------------------------------------
__device__ void zt_task(int t, int tid, unsigned short* shm,
    const unsigned short* Xb, const unsigned short* WtT,
    const float* b_tune, float* zt)
{
    const int cb = t >> 4, rb = t & 15;
    unsigned short* As = shm; unsigned short* Bs = shm + 64 * LP;
    const int srow = tid >> 2, skc = (tid & 3) << 4;
    const unsigned short* ag = Xb  + (size_t)(rb * 64 + srow) * 192 + skc;
    const unsigned short* bg = WtT + (size_t)(cb * 64 + srow) * 192 + skc;
    const int lane = tid & 63, w = tid >> 6;
    const int wrow = (w >> 1) * 32, wcol = (w & 1) * 32;
    const int fr = lane & 15, fg = lane >> 4, fk = fg << 3;

    f32x4 acc[2][2] = {};
    core_sa(ag, bg, As, Bs, 192, srow, skc, wrow, wcol, fr, fk, acc);

    #pragma unroll
    for (int m = 0; m < 2; ++m) {
        const int gm = rb * 64 + wrow + m * 16 + fg * 4;
        #pragma unroll
        for (int n = 0; n < 2; ++n) {
            const int gj = cb * 64 + wcol + n * 16 + fr;
            const float bb = b_tune[gj];
            #pragma unroll
            for (int r = 0; r < 4; ++r)
                zt[(size_t)(gm + r) * HDIM + gj] = acc[m][n][r] + bb;
        }
    }
}

// ---------------------------------------------------------------------------
// 128-wide row reduction (per 128-thread group; whole 256-thread block syncs)
// ---------------------------------------------------------------------------
__device__ __forceinline__ float rowsum128(float v, float* red, int j)
{
    #pragma unroll
    for (int o = 32; o > 0; o >>= 1) v += __shfl_xor(v, o, 64);
    if ((j & 63) == 0) red[j >> 6] = v;
    __syncthreads();
    const float t = red[0] + red[1];
    __syncthreads();
    return t;
}

__device__ __forceinline__ void rms_core(
    float x, int i, int j,
    const float* rms_scale, const float* W_dt, const float* b_dt,
    const float* A_log, const float* m_vec, const int* act,
    unsigned short* xnb, float* VU, unsigned short* VUt, float* dlt, float* red)
{
    const float ss = rowsum128(x * x, red, j);
    const float rms = sqrtf(ss) * 0.08838834764831845f;   // /sqrt(128)
    const float xn = rms_scale[j] * x / (rms + 1e-8f);
    const float dsum = rowsum128(xn * W_dt[j], red, j);
    const float dd = dsum + b_dt[0];
    const float delta = dd > 0.f ? dd + log1pf(expf(-dd)) : log1pf(expf(dd));
    xnb[(size_t)i * HDIM + j] = f2bf(xn);
    const float U = m_vec[(size_t)act[i] * HDIM + j] * expf(-delta * expf(A_log[j]));
    VU[(size_t)i * 256 + 128 + j] = U;
    VUt[(size_t)(128 + j) * 1024 + i] = f2bf(U);
    if (j == 0) dlt[i] = delta;
}

__device__ __forceinline__ float post_elem(float y1, float y2, float y3, float s,
                                           float g, float u, float dA)
{
    const float bl = -0.1f * y1 + 0.01f * y2;
    const float cq = 0.005f * y3;
    float integ = 0.f;
    #pragma unroll
    for (int k = 0; k < 8; ++k) {
        const float t = c_t[k];
        integ += c_w[k] * (g + t * bl + t * t * cq) * expf(dA * t);
    }
    return u - 0.1f * s + integ;
}

// ---------------------------------------------------------------------------
// bz2 task (t in [0,32)): V = (xnb @ WBT^T + b_B) * dlt
// ---------------------------------------------------------------------------
__device__ void bz2_task(int t, int tid, unsigned short* shm,
    const unsigned short* xnb, const unsigned short* WBT,
    const float* b_B, const float* dlt, float* VU, unsigned short* VUt)
{
    const int cb = t >> 4, rb = t & 15;
    unsigned short* As = shm; unsigned short* Bs = shm + 64 * LP;
    const int srow = tid >> 2, skc = (tid & 3) << 4;
    const unsigned short* ag = xnb + (size_t)(rb * 64 + srow) * HDIM + skc;
    const unsigned short* bg = WBT + (size_t)(cb * 64 + srow) * HDIM + skc;
    const int lane = tid & 63, w = tid >> 6;
    const int wrow = (w >> 1) * 32, wcol = (w & 1) * 32;
    const int fr = lane & 15, fg = lane >> 4, fk = fg << 3;

    f32x4 acc[2][2] = {};
    core_sa(ag, bg, As, Bs, 128, srow, skc, wrow, wcol, fr, fk, acc);

    #pragma unroll
    for (int m = 0; m < 2; ++m) {
        const int gm = rb * 64 + wrow + m * 16 + fg * 4;
        #pragma unroll
        for (int n = 0; n < 2; ++n) {
            const int col = cb * 64 + wcol + n * 16 + fr;
            const float bb = b_B[col];
            float vv[4];
            #pragma unroll
            for (int r = 0; r < 4; ++r) {
                vv[r] = (acc[m][n][r] + bb) * dlt[gm + r];
                VU[(size_t)(gm + r) * 256 + col] = vv[r];
            }
            ushort4 tv;
            tv.x = f2bf(vv[0]); tv.y = f2bf(vv[1]); tv.z = f2bf(vv[2]); tv.w = f2bf(vv[3]);
            *(ushort4*)&VUt[(size_t)col * 1024 + gm] = tv;
        }
    }
}

// ---------------------------------------------------------------------------
// GA task (t in [0,128)): slots 0,1 -> G = V-0.1LV ; 2,3 -> T = U-0.1LU-0.05dLU
// ---------------------------------------------------------------------------
__device__ void ga_task(int t, int tid, unsigned short* shm,
    const unsigned short* Lb, const unsigned short* dLb,
    const unsigned short* VUt, const float* VU,
    unsigned short* GTt, float* Gf)
{
    const int slot = t >> 5, rb = t & 31;
    const bool typeT = slot >= 2;
    const int cb = typeT ? slot - 2 : slot;
    const int bn0 = (typeT ? 128 : 0) + cb * 64;

    unsigned short* AsL = shm;
    unsigned short* AsD = shm + 32 * LP;
    unsigned short* Bs  = shm + 64 * LP;

    const int sar = tid >> 3, sac = (tid & 7) << 3;
    const int sbr = tid >> 2, sbc = (tid & 3) << 4;

    const unsigned short* aL = Lb  + (size_t)(rb * 32 + sar) * 1024 + sac;
    const unsigned short* aD = dLb + (size_t)(rb * 32 + sar) * 1024 + sac;
    const unsigned short* bg = VUt + (size_t)(bn0 + sbr) * 1024 + sbc;

    const int lane = tid & 63, w = tid >> 6;
    const int fr = lane & 15, fg = lane >> 4, fk = fg << 3;

    f32x4 acc[2] = {};
    f32x4 acc2[2] = {};

    bf16x8 pa = *(const bf16x8*)aL;
    bf16x8 pd = {};
    if (typeT) pd = *(const bf16x8*)aD;
    bf16x8 pb0 = *(const bf16x8*)bg, pb1 = *(const bf16x8*)(bg + 8);

    for (int k0 = 0; k0 < 1024; k0 += 64) {
        __syncthreads();
        *(bf16x8*)&AsL[sar * LP + sac] = pa;
        if (typeT) *(bf16x8*)&AsD[sar * LP + sac] = pd;
        *(bf16x8*)&Bs[sbr * LP + sbc] = pb0; *(bf16x8*)&Bs[sbr * LP + sbc + 8] = pb1;
        __syncthreads();
        if (k0 + 64 < 1024) {
            pa = *(const bf16x8*)(aL + k0 + 64);
            if (typeT) pd = *(const bf16x8*)(aD + k0 + 64);
            pb0 = *(const bf16x8*)(bg + k0 + 64); pb1 = *(const bf16x8*)(bg + k0 + 72);
        }
        #pragma unroll
        for (int h = 0; h < 2; ++h) {
            const int ko = h * 32 + fk;
            bf16x8 a0 = *(const bf16x8*)&AsL[fr * LP + ko];
            bf16x8 a1 = *(const bf16x8*)&AsL[(16 + fr) * LP + ko];
            bf16x8 b0 = *(const bf16x8*)&Bs[(w * 16 + fr) * LP + ko];
            acc[0] = __builtin_amdgcn_mfma_f32_16x16x32_bf16(a0, b0, acc[0], 0, 0, 0);
            acc[1] = __builtin_amdgcn_mfma_f32_16x16x32_bf16(a1, b0, acc[1], 0, 0, 0);
            if (typeT) {
                bf16x8 d0 = *(const bf16x8*)&AsD[fr * LP + ko];
                bf16x8 d1 = *(const bf16x8*)&AsD[(16 + fr) * LP + ko];
                acc2[0] = __builtin_amdgcn_mfma_f32_16x16x32_bf16(d0, b0, acc2[0], 0, 0, 0);
                acc2[1] = __builtin_amdgcn_mfma_f32_16x16x32_bf16(d1, b0, acc2[1], 0, 0, 0);
            }
        }
    }

    #pragma unroll
    for (int m = 0; m < 2; ++m) {
        const int gm = rb * 32 + m * 16 + fg * 4;
        const int gj = cb * 64 + w * 16 + fr;
        float gv[4];
        #pragma unroll
        for (int r = 0; r < 4; ++r) {
            if (!typeT)
                gv[r] = VU[(size_t)(gm + r) * 256 + gj] - 0.1f * acc[m][r];
            else
                gv[r] = VU[(size_t)(gm + r) * 256 + 128 + gj]
                      - 0.1f * acc[m][r] - 0.05f * acc2[m][r];
        }
        ushort4 tv; tv.x = f2bf(gv[0]); tv.y = f2bf(gv[1]); tv.z = f2bf(gv[2]); tv.w = f2bf(gv[3]);
        *(ushort4*)&GTt[(size_t)((typeT ? 128 : 0) + gj) * 1024 + gm] = tv;
        if (!typeT) {
            #pragma unroll
            for (int r = 0; r < 4; ++r) Gf[(size_t)(gm + r) * 128 + gj] = gv[r];
        }
    }
}

// ---------------------------------------------------------------------------
// GB task (t in [0,128)): unit0 Y1=dL@G, unit1 Y2=P1@G, unit2 Y3=P2@G, unit3 S=dL@T
// ---------------------------------------------------------------------------
__device__ void gb_task(int t, int tid, unsigned short* shm,
    const unsigned short* dLb, const unsigned short* P1b,
    const unsigned short* P2b, const unsigned short* GTt,
    float* Y1f, float* Y2f, float* Y3f, float* Sf)
{
    const int bx = t >> 4, rb = t & 15;
    const int unit = bx >> 1, cb = bx & 1;
    const unsigned short* A = (unit == 1) ? P1b : (unit == 2) ? P2b : dLb;
    const int bn0 = (unit == 3 ? 128 : 0) + cb * 64;
    float* O = unit == 0 ? Y1f : unit == 1 ? Y2f : unit == 2 ? Y3f : Sf;

    unsigned short* As = shm; unsigned short* Bs = shm + 64 * LP;
    const int srow = tid >> 2, skc = (tid & 3) << 4;
    const unsigned short* ag = A   + (size_t)(rb * 64 + srow) * 1024 + skc;
    const unsigned short* bg = GTt + (size_t)(bn0 + srow) * 1024 + skc;

    const int lane = tid & 63, w = tid >> 6;
    const int wrow = (w >> 1) * 32, wcol = (w & 1) * 32;
    const int fr = lane & 15, fg = lane >> 4, fk = fg << 3;

    f32x4 acc[2][2] = {};
    core_sa(ag, bg, As, Bs, 1024, srow, skc, wrow, wcol, fr, fk, acc);

    #pragma unroll
    for (int m = 0; m < 2; ++m) {
        const int gm = rb * 64 + wrow + m * 16 + fg * 4;
        #pragma unroll
        for (int n = 0; n < 2; ++n) {
            const int gj = cb * 64 + wcol + n * 16 + fr;
            #pragma unroll
            for (int r = 0; r < 4; ++r) O[(size_t)(gm + r) * 128 + gj] = acc[m][n][r];
        }
    }
}

// ---------------------------------------------------------------------------
// the mega kernel: 11 phases, 10 grid barriers
// ---------------------------------------------------------------------------
__global__ __launch_bounds__(256)
void mega(const float* L, const float* dL, const float* x_sub,
          const float* m1, const float* m2, const float* names,
          const float* rms1, const float* rms2,
          const float* W_tune, const float* b_tune,
          const float* W_B1, const float* b_B1,
          const float* W_B2, const float* b_B2,
          const float* W_dt, const float* b_dt,
          const float* A1, const float* A2,
          const int* src, const int* dst, const int* act,
          float* zt, float* VU, float* Gf, float* Y1f, float* Y2f,
          float* Y3f, float* Sf, float* dlt1, float* dlt2,
          unsigned short* Lb, unsigned short* dLb, unsigned short* LbT,
          unsigned short* dLbT, unsigned short* P1b, unsigned short* P2b,
          unsigned short* VUt, unsigned short* GTt, unsigned short* Xb,
          unsigned short* WtT, unsigned short* WB1T, unsigned short* WB2T,
          unsigned short* xnb, unsigned* sync, float* out)
{
    __shared__ unsigned short shm[128 * LP];   // 18432 B, aliased per phase
    const int bid = blockIdx.x, tid = threadIdx.x;
    const int g = tid >> 7, j = tid & 127;
    float* redf = (float*)shm;

    // ph0: conversions / transposes
    for (int t = bid; t < 3552; t += NBLK)
        conv_task(t, tid, shm, L, dL, x_sub, names, src, dst, W_tune, W_B1, W_B2,
                  Lb, dLb, LbT, dLbT, Xb, WtT, WB1T, WB2T);
    gbar(sync, 0, bid);

    // ph1: P1,P2 (512 tasks) + zt (32 tasks on blocks 0..31)
    p12_task(bid, tid, shm, LbT, dLbT, dLb, P1b, P2b);
    if (bid < 32) zt_task(bid, tid, shm, Xb, WtT, b_tune, zt);
    gbar(sync, 1, bid);

    // ph2: stage-1 pre (rms/delta/U), 2 rows per block
    {
        const int i = bid * 2 + g;
        rms_core(zt[(size_t)i * HDIM + j], i, j, rms1, W_dt, b_dt, A1, m1, act,
                 xnb, VU, VUt, dlt1, redf + 2 * g);
    }
    gbar(sync, 2, bid);

    // ph3: bz2 stage 1
    if (bid < 32) bz2_task(bid, tid, shm, xnb, WB1T, b_B1, dlt1, VU, VUt);
    gbar(sync, 3, bid);

    // ph4: GA stage 1
    if (bid < 128) ga_task(bid, tid, shm, Lb, dLb, VUt, VU, GTt, Gf);
    gbar(sync, 4, bid);

    // ph5: GB stage 1
    if (bid < 128) gb_task(bid, tid, shm, dLb, P1b, P2b, GTt, Y1f, Y2f, Y3f, Sf);
    gbar(sync, 5, bid);

    // ph6: mid — post(stage1) -> out[0]; x2 = zt+gelu; pre(stage2)
    {
        const int i = bid * 2 + g;
        const int idx = i * HDIM + j;
        const float dA = -dlt1[i] * expf(A1[j]);
        const float o1 = post_elem(Y1f[idx], Y2f[idx], Y3f[idx], Sf[idx], Gf[idx],
                                   VU[(size_t)i * 256 + 128 + j], dA);
        out[idx] = o1;
        const float g3 = o1 * o1 * o1;
        const float gel = 0.5f * o1 * (1.0f + tanhf(0.7978845608028654f * (o1 + 0.044715f * g3)));
        const float x = zt[idx] + gel;
        rms_core(x, i, j, rms2, W_dt, b_dt, A2, m2, act, xnb, VU, VUt, dlt2, redf + 2 * g);
    }
    gbar(sync, 6, bid);

    // ph7: bz2 stage 2
    if (bid < 32) bz2_task(bid, tid, shm, xnb, WB2T, b_B2, dlt2, VU, VUt);
    gbar(sync, 7, bid);

    // ph8: GA stage 2
    if (bid < 128) ga_task(bid, tid, shm, Lb, dLb, VUt, VU, GTt, Gf);
    gbar(sync, 8, bid);

    // ph9: GB stage 2
    if (bid < 128) gb_task(bid, tid, shm, dLb, P1b, P2b, GTt, Y1f, Y2f, Y3f, Sf);
    gbar(sync, 9, bid);

    // ph10: tail — post(stage2) -> out[1]
    {
        const int idx = bid * 256 + tid;        // 512*256 = 131072 exactly
        const int i = idx >> 7, jj = idx & 127;
        const float dA = -dlt2[i] * expf(A2[jj]);
        out[131072 + idx] = post_elem(Y1f[idx], Y2f[idx], Y3f[idx], Sf[idx], Gf[idx],
                                      VU[(size_t)i * 256 + 128 + jj], dA);
    }
}

// ---------------------------------------------------------------------------
extern "C" void kernel_launch(void* const* d_in, const int* in_sizes, int n_in,
                              void* d_out, int out_size, void* d_ws, size_t ws_size,
                              hipStream_t stream)
{
    const float* L      = (const float*)d_in[0];
    const float* dL     = (const float*)d_in[1];
    const float* x_sub  = (const float*)d_in[2];
    const float* m1     = (const float*)d_in[3];
    const float* m2     = (const float*)d_in[4];
    const float* names  = (const float*)d_in[5];
    const float* rms1   = (const float*)d_in[6];
    const float* rms2   = (const float*)d_in[7];
    const float* W_tune = (const float*)d_in[8];
    const float* b_tune = (const float*)d_in[9];
    const float* W_B1   = (const float*)d_in[10];
    const float* b_B1   = (const float*)d_in[11];
    const float* W_B2   = (const float*)d_in[12];
    const float* b_B2   = (const float*)d_in[13];
    const float* W_dt   = (const float*)d_in[14];
    const float* b_dt   = (const float*)d_in[15];
    const float* A1     = (const float*)d_in[16];
    const float* A2     = (const float*)d_in[17];
    const int*   src    = (const int*)d_in[18];
    const int*   dst    = (const int*)d_in[19];
    const int*   act    = (const int*)d_in[20];
    float* out = (float*)d_out;

    // Workspace layout (~19 MB): 8 KB sync area first, then buffers
    unsigned* sync = (unsigned*)d_ws;
    float* ws   = (float*)((char*)d_ws + 8192);
    float* zt   = ws;                    // 131072
    float* VU   = zt   + 131072;         // 262144  fp32 [V|U]
    float* Gf   = VU   + 262144;         // 131072
    float* Y1f  = Gf   + 131072;         // 131072
    float* Y2f  = Y1f  + 131072;         // 131072
    float* Y3f  = Y2f  + 131072;         // 131072
    float* Sf   = Y3f  + 131072;         // 131072
    float* dlt1 = Sf   + 131072;         // 1024
    float* dlt2 = dlt1 + 1024;           // 1024
    unsigned short* Lb    = (unsigned short*)(dlt2 + 1024);
    unsigned short* dLb   = Lb    + 1048576;
    unsigned short* LbT   = dLb   + 1048576;
    unsigned short* dLbT  = LbT   + 1048576;
    unsigned short* P1b   = dLbT  + 1048576;
    unsigned short* P2b   = P1b   + 1048576;
    unsigned short* VUt   = P2b   + 1048576;
    unsigned short* GTt   = VUt   + 262144;
    unsigned short* Xb    = GTt   + 262144;
    unsigned short* WtT   = Xb    + 196608;
    unsigned short* WB1T  = WtT   + 24576;
    unsigned short* WB2T  = WB1T  + 16384;
    unsigned short* xnb   = WB2T  + 16384;

    hipMemsetAsync(sync, 0, 8192, stream);

    mega<<<dim3(NBLK), dim3(256), 0, stream>>>(
        L, dL, x_sub, m1, m2, names, rms1, rms2, W_tune, b_tune,
        W_B1, b_B1, W_B2, b_B2, W_dt, b_dt, A1, A2, src, dst, act,
        zt, VU, Gf, Y1f, Y2f, Y3f, Sf, dlt1, dlt2,
        Lb, dLb, LbT, dLbT, P1b, P2b, VUt, GTt, Xb, WtT, WB1T, WB2T,
        xnb, sync, out);
}

// Round 13
// 77.456 us; speedup vs baseline: 13.9245x; 3.1029x over previous
//
#include <hip/hip_runtime.h>
#include <math.h>

#define N_A   1024
#define HDIM  128
#define DIN   172
#define E_CNT 256
#define LP    72      // LDS pitch (bf16) for 64-wide GEMM tiles

typedef __attribute__((ext_vector_type(8))) short bf16x8;
typedef __attribute__((ext_vector_type(4))) float f32x4;

__device__ __forceinline__ unsigned short f2bf(float x) {
    unsigned int u = __float_as_uint(x);
    unsigned int r = (u + 0x7fffu + ((u >> 16) & 1u)) >> 16;
    return (unsigned short)r;
}
__device__ __forceinline__ float bf2f(unsigned short x) {
    return __uint_as_float((unsigned int)x << 16);
}

// Gauss-Legendre nodes/weights mapped to [0,1] (tau=1)
__constant__ float c_t[8] = {
    0.4082826787521751f, 0.2372337950418355f, 0.10166676129318665f, 0.019855071751231843f,
    0.5917173212478249f, 0.7627662049581645f, 0.8983332387068134f, 0.9801449282487682f};
__constant__ float c_w[8] = {
    0.181341891689181f, 0.15685332293894365f, 0.11119051722668725f, 0.05061426814518815f,
    0.181341891689181f, 0.15685332293894365f, 0.11119051722668725f, 0.05061426814518815f};

// ---------------------------------------------------------------------------
// conv_all: fp32 -> bf16 conversions / transposes (verbatim round 10)
// ---------------------------------------------------------------------------
__global__ __launch_bounds__(256)
void conv_all(const float* __restrict__ L, const float* __restrict__ dL,
              const float* __restrict__ x_sub, const float* __restrict__ names,
              const int* __restrict__ src, const int* __restrict__ dst,
              const float* __restrict__ W_tune, const float* __restrict__ W_B1,
              const float* __restrict__ W_B2,
              unsigned short* __restrict__ Lb, unsigned short* __restrict__ dLb,
              unsigned short* __restrict__ LbT, unsigned short* __restrict__ dLbT,
              unsigned short* __restrict__ Xb, unsigned short* __restrict__ WtT,
              unsigned short* __restrict__ WB1T, unsigned short* __restrict__ WB2T)
{
    __shared__ unsigned short tl[64][72];
    const int b = blockIdx.x, tid = threadIdx.x;
    if (b < 2048) {
        const int t = b * 256 + tid;
        const float* s = (t < 262144) ? L : dL;
        unsigned short* d = (t < 262144) ? Lb : dLb;
        const int q = (t < 262144) ? t : t - 262144;
        float4 v = *(const float4*)(s + (size_t)q * 4);
        ushort4 o;
        o.x = f2bf(v.x); o.y = f2bf(v.y); o.z = f2bf(v.z); o.w = f2bf(v.w);
        *(ushort4*)(d + (size_t)q * 4) = o;
    } else if (b < 2816) {
        const int t = (b - 2048) * 256 + tid;
        const int i = t / 192, k = t - i * 192;
        float val = 0.f;
        if (k < DIN) val = x_sub[(size_t)i * DIN + k];
        else if (k == DIN) {
            if (i < E_CNT)          val = names[src[i]];
            else if (i < 2 * E_CNT) val = names[dst[i - E_CNT]];
        } else if (k == DIN + 1) {
            if (i < E_CNT)          val = names[dst[i]];
            else if (i < 2 * E_CNT) val = names[src[i - E_CNT]];
        }
        Xb[t] = f2bf(val);
    } else if (b < 2912) {
        const int t = (b - 2816) * 256 + tid;
        const int j = t / 192, k = t - j * 192;
        WtT[t] = (k < DIN + 2) ? f2bf(W_tune[k * HDIM + j]) : (unsigned short)0;
    } else if (b < 3040) {
        const int t = (b - 2912) * 256 + tid;
        const int half = t >> 14, tt = t & 16383;
        const int j = tt >> 7, k = tt & 127;
        (half ? WB2T : WB1T)[tt] = f2bf((half ? W_B2 : W_B1)[k * HDIM + j]);
    } else {
        const int t = b - 3040;                      // 0..511
        const float* s = (t < 256) ? L : dL;
        unsigned short* d = (t < 256) ? LbT : dLbT;
        const int tile = t & 255, tr = tile >> 4, tc = tile & 15;
        const int row = tid >> 2, cg = (tid & 3) << 4;
        #pragma unroll
        for (int e = 0; e < 4; ++e) {
            float4 v = *(const float4*)(s + (size_t)(tr * 64 + row) * 1024 + tc * 64 + cg + e * 4);
            tl[row][cg + e * 4 + 0] = f2bf(v.x);
            tl[row][cg + e * 4 + 1] = f2bf(v.y);
            tl[row][cg + e * 4 + 2] = f2bf(v.z);
            tl[row][cg + e * 4 + 3] = f2bf(v.w);
        }
        __syncthreads();
        unsigned short* drow = d + (size_t)(tc * 64 + row) * 1024 + tr * 64 + cg;
        #pragma unroll
        for (int e = 0; e < 4; ++e) {
            ushort4 o;
            o.x = tl[cg + e * 4 + 0][row];
            o.y = tl[cg + e * 4 + 1][row];
            o.z = tl[cg + e * 4 + 2][row];
            o.w = tl[cg + e * 4 + 3][row];
            *(ushort4*)(drow + e * 4) = o;
        }
    }
}

// ---------------------------------------------------------------------------
// single-A 64x64 MFMA core (verbatim)
// ---------------------------------------------------------------------------
__device__ __forceinline__ void core_sa(
    const unsigned short* __restrict__ ag, const unsigned short* __restrict__ bg,
    unsigned short* As, unsigned short* Bs, int klen,
    int srow, int skc, int wrow, int wcol, int fr, int fk, f32x4 (&acc)[2][2])
{
    bf16x8 pa0 = *(const bf16x8*)ag, pa1 = *(const bf16x8*)(ag + 8);
    bf16x8 pb0 = *(const bf16x8*)bg, pb1 = *(const bf16x8*)(bg + 8);
    for (int k0 = 0; k0 < klen; k0 += 64) {
        __syncthreads();
        *(bf16x8*)&As[srow * LP + skc] = pa0; *(bf16x8*)&As[srow * LP + skc + 8] = pa1;
        *(bf16x8*)&Bs[srow * LP + skc] = pb0; *(bf16x8*)&Bs[srow * LP + skc + 8] = pb1;
        __syncthreads();
        if (k0 + 64 < klen) {
            pa0 = *(const bf16x8*)(ag + k0 + 64); pa1 = *(const bf16x8*)(ag + k0 + 72);
            pb0 = *(const bf16x8*)(bg + k0 + 64); pb1 = *(const bf16x8*)(bg + k0 + 72);
        }
        #pragma unroll
        for (int h = 0; h < 2; ++h) {
            const int ko = h * 32 + fk;
            bf16x8 a0 = *(const bf16x8*)&As[(wrow + fr) * LP + ko];
            bf16x8 a1 = *(const bf16x8*)&As[(wrow + 16 + fr) * LP + ko];
            bf16x8 b0 = *(const bf16x8*)&Bs[(wcol + fr) * LP + ko];
            bf16x8 b1 = *(const bf16x8*)&Bs[(wcol + 16 + fr) * LP + ko];
            acc[0][0] = __builtin_amdgcn_mfma_f32_16x16x32_bf16(a0, b0, acc[0][0], 0, 0, 0);
            acc[0][1] = __builtin_amdgcn_mfma_f32_16x16x32_bf16(a0, b1, acc[0][1], 0, 0, 0);
            acc[1][0] = __builtin_amdgcn_mfma_f32_16x16x32_bf16(a1, b0, acc[1][0], 0, 0, 0);
            acc[1][1] = __builtin_amdgcn_mfma_f32_16x16x32_bf16(a1, b1, acc[1][1], 0, 0, 0);
        }
    }
}

// ---------------------------------------------------------------------------
// k_d2: blocks 0..511: P1 = dL@L, P2 = dL@dL (transpose trick)
//       blocks 512..543: zt = Xb @ WtT^T + b_tune
// ---------------------------------------------------------------------------
__global__ __launch_bounds__(256)
void k_d2(const unsigned short* __restrict__ LbT, const unsigned short* __restrict__ dLbT,
          const unsigned short* __restrict__ dLb,
          unsigned short* __restrict__ P1b, unsigned short* __restrict__ P2b,
          const unsigned short* __restrict__ Xb, const unsigned short* __restrict__ WtT,
          const float* __restrict__ b_tune, float* __restrict__ zt)
{
    __shared__ unsigned short shm[128 * LP];
    unsigned short* As = shm; unsigned short* Bs = shm + 64 * LP;
    const int bid = blockIdx.x, tid = threadIdx.x;
    const int srow = tid >> 2, skc = (tid & 3) << 4;
    const int lane = tid & 63, w = tid >> 6;
    const int wrow = (w >> 1) * 32, wcol = (w & 1) * 32;
    const int fr = lane & 15, fg = lane >> 4, fk = fg << 3;

    if (bid < 512) {
        const int bx = bid >> 4, rb = bid & 15;
        const int unit = bx >> 4, cb = bx & 15;
        const unsigned short* A = unit ? dLbT : LbT;
        unsigned short* O = unit ? P2b : P1b;
        const unsigned short* ag = A   + (size_t)(rb * 64 + srow) * 1024 + skc;
        const unsigned short* bg = dLb + (size_t)(cb * 64 + srow) * 1024 + skc;
        f32x4 acc[2][2] = {};
        core_sa(ag, bg, As, Bs, 1024, srow, skc, wrow, wcol, fr, fk, acc);
        #pragma unroll
        for (int m = 0; m < 2; ++m) {
            const int gm = rb * 64 + wrow + m * 16 + fg * 4;       // i
            #pragma unroll
            for (int n = 0; n < 2; ++n) {
                const int gj = cb * 64 + wcol + n * 16 + fr;       // m
                ushort4 tv;
                tv.x = f2bf(acc[m][n][0]); tv.y = f2bf(acc[m][n][1]);
                tv.z = f2bf(acc[m][n][2]); tv.w = f2bf(acc[m][n][3]);
                *(ushort4*)&O[(size_t)gj * 1024 + gm] = tv;        // O[m][i]
            }
        }
    } else {
        const int t = bid - 512;                 // 0..31
        const int cb = t >> 4, rb = t & 15;
        const unsigned short* ag = Xb  + (size_t)(rb * 64 + srow) * 192 + skc;
        const unsigned short* bg = WtT + (size_t)(cb * 64 + srow) * 192 + skc;
        f32x4 acc[2][2] = {};
        core_sa(ag, bg, As, Bs, 192, srow, skc, wrow, wcol, fr, fk, acc);
        #pragma unroll
        for (int m = 0; m < 2; ++m) {
            const int gm = rb * 64 + wrow + m * 16 + fg * 4;
            #pragma unroll
            for (int n = 0; n < 2; ++n) {
                const int gj = cb * 64 + wcol + n * 16 + fr;
                const float bb = b_tune[gj];
                #pragma unroll
                for (int r = 0; r < 4; ++r)
                    zt[(size_t)(gm + r) * HDIM + gj] = acc[m][n][r] + bb;
            }
        }
    }
}

// ---------------------------------------------------------------------------
// row-wise helpers (verbatim round 10 / mega ph2)
// ---------------------------------------------------------------------------
__device__ __forceinline__ float rowsum128(float v, float* red, int j)
{
    #pragma unroll
    for (int o = 32; o > 0; o >>= 1) v += __shfl_xor(v, o, 64);
    if ((j & 63) == 0) red[j >> 6] = v;
    __syncthreads();
    const float t = red[0] + red[1];
    __syncthreads();
    return t;
}

__device__ __forceinline__ void rms_core(
    float x, int i, int j,
    const float* rms_scale, const float* W_dt, const float* b_dt,
    const float* A_log, const float* m_vec, const int* act,
    unsigned short* xnb, float* VU, unsigned short* VUt, float* dlt, float* red)
{
    const float ss = rowsum128(x * x, red, j);
    const float rms = sqrtf(ss) * 0.08838834764831845f;   // /sqrt(128)
    const float xn = rms_scale[j] * x / (rms + 1e-8f);
    const float dsum = rowsum128(xn * W_dt[j], red, j);
    const float dd = dsum + b_dt[0];
    const float delta = dd > 0.f ? dd + log1pf(expf(-dd)) : log1pf(expf(dd));
    xnb[(size_t)i * HDIM + j] = f2bf(xn);
    const float U = m_vec[(size_t)act[i] * HDIM + j] * expf(-delta * expf(A_log[j]));
    VU[(size_t)i * 256 + 128 + j] = U;
    VUt[(size_t)(128 + j) * 1024 + i] = f2bf(U);
    if (j == 0) dlt[i] = delta;
}

__device__ __forceinline__ float post_elem(float y1, float y2, float y3, float s,
                                           float g, float u, float dA)
{
    const float bl = -0.1f * y1 + 0.01f * y2;
    const float cq = 0.005f * y3;
    float integ = 0.f;
    #pragma unroll
    for (int k = 0; k < 8; ++k) {
        const float t = c_t[k];
        integ += c_w[k] * (g + t * bl + t * t * cq) * expf(dA * t);
    }
    return u - 0.1f * s + integ;
}

// ---------------------------------------------------------------------------
// k_d3: blocks 0..511: M2 = P1 - 0.1*(P1@L), M3 = P2 - 0.1*(P2@L)
//       (transpose trick, A=LbT, Bt=P1b/P2b, epilogue reads P1b/P2b)
//       blocks 512..1023: stage-1 rms/delta/U (2 rows per block)
// ---------------------------------------------------------------------------
__global__ __launch_bounds__(256)
void k_d3(const unsigned short* __restrict__ LbT,
          const unsigned short* __restrict__ P1b, const unsigned short* __restrict__ P2b,
          unsigned short* __restrict__ M2b, unsigned short* __restrict__ M3b,
          const float* __restrict__ zt,
          const float* __restrict__ rms1, const float* __restrict__ W_dt,
          const float* __restrict__ b_dt, const float* __restrict__ A1,
          const float* __restrict__ m1, const int* __restrict__ act,
          unsigned short* __restrict__ xnb, float* __restrict__ VU,
          unsigned short* __restrict__ VUt, float* __restrict__ dlt1)
{
    __shared__ unsigned short shm[128 * LP];
    const int bid = blockIdx.x, tid = threadIdx.x;

    if (bid < 512) {
        unsigned short* As = shm; unsigned short* Bs = shm + 64 * LP;
        const int srow = tid >> 2, skc = (tid & 3) << 4;
        const int lane = tid & 63, w = tid >> 6;
        const int wrow = (w >> 1) * 32, wcol = (w & 1) * 32;
        const int fr = lane & 15, fg = lane >> 4, fk = fg << 3;
        const int bx = bid >> 4, rb = bid & 15;
        const int unit = bx >> 4, cb = bx & 15;
        const unsigned short* Bt = unit ? P2b : P1b;
        const unsigned short* Src = unit ? P2b : P1b;
        unsigned short* O = unit ? M3b : M2b;
        const unsigned short* ag = LbT + (size_t)(rb * 64 + srow) * 1024 + skc;
        const unsigned short* bg = Bt  + (size_t)(cb * 64 + srow) * 1024 + skc;
        f32x4 acc[2][2] = {};
        core_sa(ag, bg, As, Bs, 1024, srow, skc, wrow, wcol, fr, fk, acc);
        #pragma unroll
        for (int m = 0; m < 2; ++m) {
            const int gm = rb * 64 + wrow + m * 16 + fg * 4;       // i
            #pragma unroll
            for (int n = 0; n < 2; ++n) {
                const int gj = cb * 64 + wcol + n * 16 + fr;       // m
                ushort4 sv = *(const ushort4*)&Src[(size_t)gj * 1024 + gm];
                ushort4 tv;
                tv.x = f2bf(bf2f(sv.x) - 0.1f * acc[m][n][0]);
                tv.y = f2bf(bf2f(sv.y) - 0.1f * acc[m][n][1]);
                tv.z = f2bf(bf2f(sv.z) - 0.1f * acc[m][n][2]);
                tv.w = f2bf(bf2f(sv.w) - 0.1f * acc[m][n][3]);
                *(ushort4*)&O[(size_t)gj * 1024 + gm] = tv;        // M[m][i]
            }
        }
    } else {
        float* redf = (float*)shm;
        const int g = tid >> 7, j = tid & 127;
        const int i = (bid - 512) * 2 + g;
        rms_core(zt[(size_t)i * HDIM + j], i, j, rms1, W_dt, b_dt, A1, m1, act,
                 xnb, VU, VUt, dlt1, redf + 2 * g);
    }
}

// ---------------------------------------------------------------------------
// gemm_bz2: V = (xnb @ WBT^T + b_B) * dlt   (verbatim round 10)
// ---------------------------------------------------------------------------
__global__ __launch_bounds__(256)
void gemm_bz2(const unsigned short* __restrict__ xnb, const unsigned short* __restrict__ WBT,
              const float* __restrict__ b_B, const float* __restrict__ dlt,
              float* __restrict__ VU, unsigned short* __restrict__ VUt)
{
    const int cb = blockIdx.x, rb = blockIdx.y;
    __shared__ unsigned short As[64 * LP];
    __shared__ unsigned short Bs[64 * LP];
    const int tid = threadIdx.x, srow = tid >> 2, skc = (tid & 3) << 4;
    const unsigned short* ag = xnb + (size_t)(rb * 64 + srow) * HDIM + skc;
    const unsigned short* bg = WBT + (size_t)(cb * 64 + srow) * HDIM + skc;
    const int lane = tid & 63, w = tid >> 6;
    const int wrow = (w >> 1) * 32, wcol = (w & 1) * 32;
    const int fr = lane & 15, fg = lane >> 4, fk = fg << 3;

    f32x4 acc[2][2] = {};
    core_sa(ag, bg, As, Bs, 128, srow, skc, wrow, wcol, fr, fk, acc);

    #pragma unroll
    for (int m = 0; m < 2; ++m) {
        const int gm = rb * 64 + wrow + m * 16 + fg * 4;
        #pragma unroll
        for (int n = 0; n < 2; ++n) {
            const int col = cb * 64 + wcol + n * 16 + fr;
            const float bb = b_B[col];
            float vv[4];
            #pragma unroll
            for (int r = 0; r < 4; ++r) {
                vv[r] = (acc[m][n][r] + bb) * dlt[gm + r];
                VU[(size_t)(gm + r) * 256 + col] = vv[r];
            }
            ushort4 tv;
            tv.x = f2bf(vv[0]); tv.y = f2bf(vv[1]); tv.z = f2bf(vv[2]); tv.w = f2bf(vv[3]);
            *(ushort4*)&VUt[(size_t)col * 1024 + gm] = tv;
        }
    }
}

// ---------------------------------------------------------------------------
// k_big: one dispatch, 8 units x 32 rb x 2 cb = 512 blocks; 32x64 tiles.
//  unit: 0 L@V (->Gf = V-0.1*acc), 1 dL@V, 2 P1@V, 3 M2@V, 4 M3@V,
//        5 dL@U, 6 P1@U, 7 P2@U
// ---------------------------------------------------------------------------
__global__ __launch_bounds__(256)
void k_big(const unsigned short* __restrict__ Lb, const unsigned short* __restrict__ dLb,
           const unsigned short* __restrict__ P1b, const unsigned short* __restrict__ P2b,
           const unsigned short* __restrict__ M2b, const unsigned short* __restrict__ M3b,
           const unsigned short* __restrict__ VUt, const float* __restrict__ VU,
           float* __restrict__ Gf, float* __restrict__ dLVf, float* __restrict__ P1Vf,
           float* __restrict__ Y2f, float* __restrict__ Y3f, float* __restrict__ dLUf,
           float* __restrict__ P1Uf, float* __restrict__ P2Uf)
{
    __shared__ unsigned short shm[96 * LP];
    unsigned short* AsL = shm;                 // 32 x LP
    unsigned short* Bs  = shm + 32 * LP;       // 64 x LP

    const int bid = blockIdx.x, tid = threadIdx.x;
    const int unit = bid >> 6, rem = bid & 63;
    const int rb = rem >> 1, cb = rem & 1;

    const unsigned short* A;
    float* O;
    switch (unit) {
        case 0: A = Lb;  O = Gf;   break;
        case 1: A = dLb; O = dLVf; break;
        case 2: A = P1b; O = P1Vf; break;
        case 3: A = M2b; O = Y2f;  break;
        case 4: A = M3b; O = Y3f;  break;
        case 5: A = dLb; O = dLUf; break;
        case 6: A = P1b; O = P1Uf; break;
        default: A = P2b; O = P2Uf; break;
    }
    const int bn0 = ((unit >= 5) ? 128 : 0) + cb * 64;

    const int sar = tid >> 3, sac = (tid & 7) << 3;    // A: 32 rows x 64 k
    const int sbr = tid >> 2, sbc = (tid & 3) << 4;    // B: 64 rows x 64 k

    const unsigned short* ag = A   + (size_t)(rb * 32 + sar) * 1024 + sac;
    const unsigned short* bg = VUt + (size_t)(bn0 + sbr) * 1024 + sbc;

    const int lane = tid & 63, w = tid >> 6;           // wave -> n offset w*16
    const int fr = lane & 15, fg = lane >> 4, fk = fg << 3;

    f32x4 acc[2] = {};
    bf16x8 pa = *(const bf16x8*)ag;
    bf16x8 pb0 = *(const bf16x8*)bg, pb1 = *(const bf16x8*)(bg + 8);

    for (int k0 = 0; k0 < 1024; k0 += 64) {
        __syncthreads();
        *(bf16x8*)&AsL[sar * LP + sac] = pa;
        *(bf16x8*)&Bs[sbr * LP + sbc] = pb0; *(bf16x8*)&Bs[sbr * LP + sbc + 8] = pb1;
        __syncthreads();
        if (k0 + 64 < 1024) {
            pa = *(const bf16x8*)(ag + k0 + 64);
            pb0 = *(const bf16x8*)(bg + k0 + 64); pb1 = *(const bf16x8*)(bg + k0 + 72);
        }
        #pragma unroll
        for (int h = 0; h < 2; ++h) {
            const int ko = h * 32 + fk;
            bf16x8 a0 = *(const bf16x8*)&AsL[fr * LP + ko];
            bf16x8 a1 = *(const bf16x8*)&AsL[(16 + fr) * LP + ko];
            bf16x8 b0 = *(const bf16x8*)&Bs[(w * 16 + fr) * LP + ko];
            acc[0] = __builtin_amdgcn_mfma_f32_16x16x32_bf16(a0, b0, acc[0], 0, 0, 0);
            acc[1] = __builtin_amdgcn_mfma_f32_16x16x32_bf16(a1, b0, acc[1], 0, 0, 0);
        }
    }

    #pragma unroll
    for (int m = 0; m < 2; ++m) {
        const int gm = rb * 32 + m * 16 + fg * 4;
        const int gj = cb * 64 + w * 16 + fr;          // 0..127
        if (unit == 0) {
            #pragma unroll
            for (int r = 0; r < 4; ++r)
                O[(size_t)(gm + r) * 128 + gj] =
                    VU[(size_t)(gm + r) * 256 + gj] - 0.1f * acc[m][r];
        } else {
            #pragma unroll
            for (int r = 0; r < 4; ++r)
                O[(size_t)(gm + r) * 128 + gj] = acc[m][r];
        }
    }
}

// ---------------------------------------------------------------------------
// k_mid: post(stage1) -> out[0]; x2 = zt + gelu; rms/delta/U (stage2).
// 512 blocks x 256 threads, 2 rows per block.
// ---------------------------------------------------------------------------
__global__ __launch_bounds__(256)
void k_mid(const float* __restrict__ Gf, const float* __restrict__ dLVf,
           const float* __restrict__ P1Vf, const float* __restrict__ Y2f,
           const float* __restrict__ Y3f, const float* __restrict__ dLUf,
           const float* __restrict__ P1Uf, const float* __restrict__ P2Uf,
           const float* __restrict__ zt, const float* __restrict__ dlt1,
           const float* __restrict__ A1,
           const float* __restrict__ rms2, const float* __restrict__ W_dt,
           const float* __restrict__ b_dt, const float* __restrict__ A2,
           const float* __restrict__ m2, const int* __restrict__ act,
           unsigned short* __restrict__ xnb, float* __restrict__ VU,
           unsigned short* __restrict__ VUt, float* __restrict__ dlt2,
           float* __restrict__ out0)
{
    __shared__ float redf[4];
    const int tid = threadIdx.x;
    const int g = tid >> 7, j = tid & 127;
    const int i = blockIdx.x * 2 + g;
    const int idx = i * HDIM + j;

    const float y1 = dLVf[idx] - 0.1f * P1Vf[idx];
    const float s  = dLUf[idx] - 0.1f * P1Uf[idx] - 0.05f * P2Uf[idx];
    const float dA = -dlt1[i] * expf(A1[j]);
    const float o1 = post_elem(y1, Y2f[idx], Y3f[idx], s, Gf[idx],
                               VU[(size_t)i * 256 + 128 + j], dA);
    out0[idx] = o1;
    const float g3 = o1 * o1 * o1;
    const float gel = 0.5f * o1 * (1.0f + tanhf(0.7978845608028654f * (o1 + 0.044715f * g3)));
    const float x = zt[idx] + gel;

    rms_core(x, i, j, rms2, W_dt, b_dt, A2, m2, act, xnb, VU, VUt, dlt2, redf + 2 * g);
}

// ---------------------------------------------------------------------------
// k_tail: post(stage2) -> out[1]
// ---------------------------------------------------------------------------
__global__ __launch_bounds__(256)
void k_tail(const float* __restrict__ Gf, const float* __restrict__ dLVf,
            const float* __restrict__ P1Vf, const float* __restrict__ Y2f,
            const float* __restrict__ Y3f, const float* __restrict__ dLUf,
            const float* __restrict__ P1Uf, const float* __restrict__ P2Uf,
            const float* __restrict__ VU, const float* __restrict__ dlt,
            const float* __restrict__ A_log, float* __restrict__ out)
{
    const int idx = blockIdx.x * 256 + threadIdx.x;    // 131072
    const int i = idx >> 7, j = idx & 127;
    const float y1 = dLVf[idx] - 0.1f * P1Vf[idx];
    const float s  = dLUf[idx] - 0.1f * P1Uf[idx] - 0.05f * P2Uf[idx];
    const float dA = -dlt[i] * expf(A_log[j]);
    out[idx] = post_elem(y1, Y2f[idx], Y3f[idx], s, Gf[idx],
                         VU[(size_t)i * 256 + 128 + j], dA);
}

// ---------------------------------------------------------------------------
extern "C" void kernel_launch(void* const* d_in, const int* in_sizes, int n_in,
                              void* d_out, int out_size, void* d_ws, size_t ws_size,
                              hipStream_t stream)
{
    const float* L      = (const float*)d_in[0];
    const float* dL     = (const float*)d_in[1];
    const float* x_sub  = (const float*)d_in[2];
    const float* m1     = (const float*)d_in[3];
    const float* m2     = (const float*)d_in[4];
    const float* names  = (const float*)d_in[5];
    const float* rms1   = (const float*)d_in[6];
    const float* rms2   = (const float*)d_in[7];
    const float* W_tune = (const float*)d_in[8];
    const float* b_tune = (const float*)d_in[9];
    const float* W_B1   = (const float*)d_in[10];
    const float* b_B1   = (const float*)d_in[11];
    const float* W_B2   = (const float*)d_in[12];
    const float* b_B2   = (const float*)d_in[13];
    const float* W_dt   = (const float*)d_in[14];
    const float* b_dt   = (const float*)d_in[15];
    const float* A1     = (const float*)d_in[16];
    const float* A2     = (const float*)d_in[17];
    const int*   src    = (const int*)d_in[18];
    const int*   dst    = (const int*)d_in[19];
    const int*   act    = (const int*)d_in[20];
    float* out = (float*)d_out;

    // Workspace layout (~22 MB). M2b aliases dLbT (dead after k_d2).
    float* ws    = (float*)d_ws;
    float* zt    = ws;                   // 131072
    float* VU    = zt    + 131072;       // 262144  fp32 [V|U]
    float* Gf    = VU    + 262144;       // 131072
    float* dLVf  = Gf    + 131072;       // 131072
    float* P1Vf  = dLVf  + 131072;       // 131072
    float* Y2f   = P1Vf  + 131072;       // 131072
    float* Y3f   = Y2f   + 131072;       // 131072
    float* dLUf  = Y3f   + 131072;       // 131072
    float* P1Uf  = dLUf  + 131072;       // 131072
    float* P2Uf  = P1Uf  + 131072;       // 131072
    float* dlt1  = P2Uf  + 131072;       // 1024
    float* dlt2  = dlt1  + 1024;         // 1024
    unsigned short* Lb    = (unsigned short*)(dlt2 + 1024);
    unsigned short* dLb   = Lb    + 1048576;
    unsigned short* LbT   = dLb   + 1048576;
    unsigned short* dLbT  = LbT   + 1048576;   // aliased by M2b after k_d2
    unsigned short* M2b   = dLbT;              // alias (dLbT dead after k_d2)
    unsigned short* P1b   = dLbT  + 1048576;
    unsigned short* P2b   = P1b   + 1048576;
    unsigned short* M3b   = P2b   + 1048576;
    unsigned short* VUt   = M3b   + 1048576;   // 262144 [V|U]^T
    unsigned short* Xb    = VUt   + 262144;    // 196608 [1024][192]
    unsigned short* WtT   = Xb    + 196608;    // 24576
    unsigned short* WB1T  = WtT   + 24576;     // 16384
    unsigned short* WB2T  = WB1T  + 16384;     // 16384
    unsigned short* xnb   = WB2T  + 16384;     // 131072

    // d1: conversions
    conv_all<<<dim3(3552), dim3(256), 0, stream>>>(
        L, dL, x_sub, names, src, dst, W_tune, W_B1, W_B2,
        Lb, dLb, LbT, dLbT, Xb, WtT, WB1T, WB2T);

    // d2: P1,P2 + zt
    k_d2<<<dim3(544), dim3(256), 0, stream>>>(
        LbT, dLbT, dLb, P1b, P2b, Xb, WtT, b_tune, zt);

    // d3: M2,M3 + stage-1 rms/delta/U
    k_d3<<<dim3(1024), dim3(256), 0, stream>>>(
        LbT, P1b, P2b, M2b, M3b, zt,
        rms1, W_dt, b_dt, A1, m1, act, xnb, VU, VUt, dlt1);

    // d4: bz stage 1
    gemm_bz2<<<dim3(2, 16), dim3(256), 0, stream>>>(xnb, WB1T, b_B1, dlt1, VU, VUt);

    // d5: BIG stage 1
    k_big<<<dim3(512), dim3(256), 0, stream>>>(
        Lb, dLb, P1b, P2b, M2b, M3b, VUt, VU,
        Gf, dLVf, P1Vf, Y2f, Y3f, dLUf, P1Uf, P2Uf);

    // d6: mid
    k_mid<<<dim3(512), dim3(256), 0, stream>>>(
        Gf, dLVf, P1Vf, Y2f, Y3f, dLUf, P1Uf, P2Uf,
        zt, dlt1, A1, rms2, W_dt, b_dt, A2, m2, act,
        xnb, VU, VUt, dlt2, out);

    // d7: bz stage 2
    gemm_bz2<<<dim3(2, 16), dim3(256), 0, stream>>>(xnb, WB2T, b_B2, dlt2, VU, VUt);

    // d8: BIG stage 2
    k_big<<<dim3(512), dim3(256), 0, stream>>>(
        Lb, dLb, P1b, P2b, M2b, M3b, VUt, VU,
        Gf, dLVf, P1Vf, Y2f, Y3f, dLUf, P1Uf, P2Uf);

    // d9: tail
    k_tail<<<dim3(512), dim3(256), 0, stream>>>(
        Gf, dLVf, P1Vf, Y2f, Y3f, dLUf, P1Uf, P2Uf,
        VU, dlt2, A2, out + 131072);
}